// Round 4
// baseline (93.215 us; speedup 1.0000x reference)
//
#include <hip/hip_runtime.h>
#include <stdint.h>

#define NQ 12
#define DIM 4096
#define NLAYERS 6
#define TPB 256

typedef float v2f __attribute__((ext_vector_type(2)));

// ---------------------------------------------------------------------------
// R16: R12 (best, 39.9us) with gate math forced onto VOP3P packed-fp32.
//   Hypothesis: hipcc scalarizes v2f elementwise fma -> 2x v_fma_f32; inline
//   asm v_pk_fma_f32/v_pk_mul_f32 halves VALU-issue time of the gates.
//   Single-variable change: pass structure/tables/layout are R12 verbatim.
//   k bits: 0-2 local (gated), 3 pack (v2f lane, gated via pack_gate),
//           4-9 lane (tid 0-5), 10-11 wave (tid 6-7).
//   Layer l: [P_c = rebase: fold CNOT A_{l-1}, cross-wave, 1 barrier]
//            gates w11,w10,w9 + pack w8
//            P_a: swap {0-3}<->{4-7}   (wave-local, lgkmcnt only)
//            gates w7,w6,w5 + pack w4
//            P_b: swap {0-3}<->{8-11}  (cross-wave, pre+post barrier)
//            gates w3,w2,w1 + pack w0
// ---------------------------------------------------------------------------
struct Pass_t {
    uint32_t WT[8];    // Lambda cols, k bits 4..11
    uint32_t WL[8];    // Lambda(j), local bits 0..2
    uint32_t RT[8];    // (Lambda o M) cols, k bits 4..11
    uint32_t RL[16];   // (Lambda o M)(l), local bits 0..3
};
struct Pass10_t {      // wave-local: 10-bit space (k bits 0..9)
    uint32_t WT[6];
    uint32_t WL[8];
    uint32_t RT[6];
    uint32_t RL[16];
};
struct CK_t {
    Pass10_t PA;           // swap {0-3}<->{4-7}, wave-local
    Pass_t PB;             // swap {0-3}<->{8-11}, cross-wave
    Pass_t P1[NLAYERS];    // rebase (index 1..5 used)
    uint32_t frow[NQ];     // epilogue sign rows
};

constexpr uint32_t G2f(uint32_t k){ return ((k&15u)<<8) | (k&0xF0u) | ((k>>8)&15u); }
constexpr uint32_t G3f(uint32_t k){ return ((k&15u)<<4) | ((k>>4)&15u) | (k&0xF00u); }

constexpr uint32_t ech_reduce(const uint32_t* v, int n, uint32_t x){
    bool ch = true;
    while (ch) {
        ch = false;
        for (int i = 0; i < n; i++)
            if (v[i] && (x ^ v[i]) < x) { x ^= v[i]; ch = true; }
    }
    return x;
}

constexpr Pass_t build_pass(const uint32_t* Mc) {
    Pass_t P{};
    uint32_t rows[12]{};
    rows[0] = 8u;                              // row0 = pack functional
    int nr = 1;
    uint32_t full[12]{}; int nf = 0; full[nf++] = 8u;
    uint32_t We[4]{};  int nw = 0;
    uint32_t Re[5]{};  int nre = 0;
    {   // row0's read projection over span Mc[4..8]
        uint32_t p0 = 0;
        for (int j = 0; j < 5; j++)
            p0 |= (uint32_t)(__builtin_popcount(8u & Mc[4 + j]) & 1) << j;
        uint32_t r = ech_reduce(Re, nre, p0);
        if (r) Re[nre++] = r;
    }
    for (int slot = 0; slot < 4; slot++) {
        uint32_t chosen = 0;
        for (int relax = 0; relax < 3 && !chosen; relax++) {
            for (uint32_t m = 1; m < 4096u && !chosen; m++) {
                if (m & 8u) continue;
                uint32_t wp = (m >> 4) & 15u;
                uint32_t wr = ech_reduce(We, nw, wp);
                if (relax < 2 && !wr) continue;
                uint32_t rp = 0;
                for (int j = 0; j < 5; j++)
                    rp |= (uint32_t)(__builtin_popcount(m & Mc[4 + j]) & 1) << j;
                uint32_t rr = ech_reduce(Re, nre, rp);
                if (relax < 1 && !rr) continue;
                uint32_t fr = ech_reduce(full, nf, m);
                if (!fr) continue;
                chosen = m; full[nf++] = fr;
                if (wr && nw < 4) We[nw++] = wr;
                if (rr && nre < 5) Re[nre++] = rr;
            }
        }
        rows[nr++] = chosen;
    }
    for (int slot = nr; slot < 12; slot++) {
        for (uint32_t m = 1; m < 4096u; m++) {
            if (m & 8u) continue;
            uint32_t fr = ech_reduce(full, nf, m);
            if (fr) { rows[slot] = m; full[nf++] = fr; break; }
        }
    }
    uint32_t col[12]{}, lmc[12]{};
    for (int j = 0; j < 12; j++) {
        uint32_t c = 0;
        for (int i = 0; i < 12; i++) c |= (uint32_t)((rows[i] >> j) & 1u) << i;
        col[j] = c;
    }
    for (int j = 0; j < 12; j++) {
        uint32_t a = 0, mc = Mc[j];
        for (int q = 0; q < 12; q++) if ((mc >> q) & 1u) a ^= col[q];
        lmc[j] = a;
    }
    for (int j = 0; j < 8; j++) { P.WT[j] = col[4 + j]; P.RT[j] = lmc[4 + j]; }
    for (int j = 0; j < 8; j++) {
        uint32_t a = 0;
        for (int q = 0; q < 3; q++) if ((j >> q) & 1) a ^= col[q];
        P.WL[j] = a;
    }
    for (int l = 0; l < 16; l++) {
        uint32_t a = 0;
        for (int q = 0; q < 4; q++) if ((l >> q) & 1) a ^= lmc[q];
        P.RL[l] = a;
    }
    return P;
}

constexpr Pass10_t build_pass10(const uint32_t* Mc) {
    Pass10_t P{};
    uint32_t rows[10]{};
    rows[0] = 8u;
    int nr = 1;
    uint32_t full[10]{}; int nf = 0; full[nf++] = 8u;
    uint32_t We[4]{};  int nw = 0;
    uint32_t Re[5]{};  int nre = 0;
    {
        uint32_t p0 = 0;
        for (int j = 0; j < 5; j++)
            p0 |= (uint32_t)(__builtin_popcount(8u & Mc[4 + j]) & 1) << j;
        uint32_t r = ech_reduce(Re, nre, p0);
        if (r) Re[nre++] = r;
    }
    for (int slot = 0; slot < 4; slot++) {
        uint32_t chosen = 0;
        for (int relax = 0; relax < 3 && !chosen; relax++) {
            for (uint32_t m = 1; m < 1024u && !chosen; m++) {
                if (m & 8u) continue;
                uint32_t wp = (m >> 4) & 15u;
                uint32_t wr = ech_reduce(We, nw, wp);
                if (relax < 2 && !wr) continue;
                uint32_t rp = 0;
                for (int j = 0; j < 5; j++)
                    rp |= (uint32_t)(__builtin_popcount(m & Mc[4 + j]) & 1) << j;
                uint32_t rr = ech_reduce(Re, nre, rp);
                if (relax < 1 && !rr) continue;
                uint32_t fr = ech_reduce(full, nf, m);
                if (!fr) continue;
                chosen = m; full[nf++] = fr;
                if (wr && nw < 4) We[nw++] = wr;
                if (rr && nre < 5) Re[nre++] = rr;
            }
        }
        rows[nr++] = chosen;
    }
    for (int slot = nr; slot < 10; slot++) {
        for (uint32_t m = 1; m < 1024u; m++) {
            if (m & 8u) continue;
            uint32_t fr = ech_reduce(full, nf, m);
            if (fr) { rows[slot] = m; full[nf++] = fr; break; }
        }
    }
    uint32_t col[10]{}, lmc[10]{};
    for (int j = 0; j < 10; j++) {
        uint32_t c = 0;
        for (int i = 0; i < 10; i++) c |= (uint32_t)((rows[i] >> j) & 1u) << i;
        col[j] = c;
    }
    for (int j = 0; j < 10; j++) {
        uint32_t a = 0, mc = Mc[j];
        for (int q = 0; q < 10; q++) if ((mc >> q) & 1u) a ^= col[q];
        lmc[j] = a;
    }
    for (int j = 0; j < 6; j++) { P.WT[j] = col[4 + j]; P.RT[j] = lmc[4 + j]; }
    for (int j = 0; j < 8; j++) {
        uint32_t a = 0;
        for (int q = 0; q < 3; q++) if ((j >> q) & 1) a ^= col[q];
        P.WL[j] = a;
    }
    for (int l = 0; l < 16; l++) {
        uint32_t a = 0;
        for (int q = 0; q < 4; q++) if ((l >> q) & 1) a ^= lmc[q];
        P.RL[l] = a;
    }
    return P;
}

constexpr CK_t build_ck() {
    CK_t ck{};
    uint32_t Acols[NLAYERS][NQ]{}, Aicol5[NQ]{};
    for (int l = 0; l < NLAYERS; l++) {
        int r = l % (NQ - 1) + 1;
        for (int q = 0; q < NQ; q++) {
            uint32_t v = 1u << q;
            for (int w = NQ - 1; w >= 0; w--) {            // A = T0∘T1∘...∘T11
                int pc = NQ - 1 - w, pt = NQ - 1 - ((w + r) % NQ);
                v ^= ((v >> pc) & 1u) << pt;
            }
            Acols[l][q] = v;
            if (l == NLAYERS - 1) {
                uint32_t u = 1u << q;
                for (int w = 0; w < NQ; w++) {             // A^-1
                    int pc = NQ - 1 - w, pt = NQ - 1 - ((w + r) % NQ);
                    u ^= ((u >> pc) & 1u) << pt;
                }
                Aicol5[q] = u;
            }
        }
    }
    uint32_t Mc10[10]{};
    for (int j = 0; j < 10; j++) Mc10[j] = G3f(1u << j);      // M_a
    ck.PA = build_pass10(Mc10);
    uint32_t Mc[12]{};
    for (int j = 0; j < 12; j++) Mc[j] = G2f(1u << j);        // M_b
    ck.PB = build_pass(Mc);
    for (int l = 1; l < NLAYERS; l++) {                       // M_c = M_b.M_a.A
        for (int j = 0; j < 12; j++) Mc[j] = G2f(G3f(Acols[l - 1][j]));
        ck.P1[l] = build_pass(Mc);
    }
    // epilogue: i(k) = A5^-1(Phi(k)), Phi = M_a.M_b  (col: G3f(G2f(e_j)))
    uint32_t Mcol[NQ]{};
    for (int j = 0; j < NQ; j++) {
        uint32_t pj = G3f(G2f(1u << j));
        uint32_t M = 0;
        for (int m = 0; m < NQ; m++) if ((pj >> m) & 1u) M ^= Aicol5[m];
        Mcol[j] = M;
    }
    for (int p = 0; p < NQ; p++) {
        uint32_t s = 0;
        for (int j = 0; j < NQ; j++) s |= ((Mcol[j] >> p) & 1u) << j;
        ck.frow[p] = s;
    }
    return ck;
}
constexpr CK_t CK = build_ck();

// ---- VOP3P packed-fp32 primitives (the single change vs R12) --------------
__device__ __forceinline__ v2f pk_mul_v(v2f a, v2f b) {
    v2f d;
    asm("v_pk_mul_f32 %0, %1, %2" : "=v"(d) : "v"(a), "v"(b));
    return d;
}
__device__ __forceinline__ v2f pk_fma_v(v2f a, v2f b, v2f c) {
    v2f d;
    asm("v_pk_fma_f32 %0, %1, %2, %3" : "=v"(d) : "v"(a), "v"(b), "v"(c));
    return d;
}

// rotation at local bit Q; m = (m00r,m00i,m01r,m01i); packed-pair math.
// Identical association to R12: out = x*s + (y')*t + (z')*u + (w')*v chains.
template<int Q>
__device__ __forceinline__ void gate_q(v2f (&PRE)[8], v2f (&PIM)[8], float4 m) {
    const float x = m.x, y = m.y, z = m.z, w = m.w;
    const float ny = -y, nz = -z, nw = -w;
    const v2f xv  = {x, x},  yv  = {y, y},  zv  = {z, z},  wv  = {w, w};
    const v2f nyv = {ny, ny}, nzv = {nz, nz}, nwv = {nw, nw};
    #pragma unroll
    for (int j = 0; j < 8; j++) {
        if (j & (1 << Q)) continue;
        int j2 = j | (1 << Q);
        v2f re0 = PRE[j], im0 = PIM[j], re1 = PRE[j2], im1 = PIM[j2];
        PRE[j]  = pk_fma_v(xv, re0, pk_fma_v(nyv, im0, pk_fma_v(zv,  re1, pk_mul_v(nwv, im1))));
        PIM[j]  = pk_fma_v(xv, im0, pk_fma_v(yv,  re0, pk_fma_v(zv,  im1, pk_mul_v(wv,  re1))));
        PRE[j2] = pk_fma_v(xv, re1, pk_fma_v(yv,  im1, pk_fma_v(nzv, re0, pk_mul_v(nwv, im0))));
        PIM[j2] = pk_fma_v(xv, im1, pk_fma_v(nyv, re1, pk_fma_v(nzv, im0, pk_mul_v(wv,  re0))));
    }
}

// gate on the pack bit (halves .x/.y of each v2f), sign-vector pk math.
//   PRE' = x*RE + d1*IM + d2*sR - w*sI ; PIM' = x*IM - d1*RE + d2*sI + w*sR
//   d1 = {-y, y}, d2 = {z, -z}; sR/sI = half-swapped RE/IM.
__device__ __forceinline__ void pack_gate(v2f (&PRE)[8], v2f (&PIM)[8], float4 m) {
    const float x = m.x, y = m.y, z = m.z, w = m.w;
    const float ny = -y, nz = -z, nw = -w;
    const v2f xv = {x, x}, wvv = {w, w}, nwv = {nw, nw};
    const v2f d1 = {ny, y}, nd1 = {y, ny}, d2 = {z, nz};
    #pragma unroll
    for (int j = 0; j < 8; j++) {
        v2f RE = PRE[j], IM = PIM[j];
        v2f sR = {RE.y, RE.x}, sI = {IM.y, IM.x};
        v2f t = pk_mul_v(xv, RE);
        t = pk_fma_v(d1, IM, t);
        t = pk_fma_v(d2, sR, t);
        PRE[j] = pk_fma_v(nwv, sI, t);
        v2f u = pk_mul_v(xv, IM);
        u = pk_fma_v(nd1, RE, u);
        u = pk_fma_v(d2, sI, u);
        PIM[j] = pk_fma_v(wvv, sR, u);
    }
}

// wave-local P_a: b64 writes, lgkmcnt drain, b32 scatter reads (R12 verbatim)
__device__ __forceinline__ void pa_pass(v2f (&PRE)[8], v2f (&PIM)[8],
                                        float* buf, uint32_t wb, uint32_t rb) {
    constexpr Pass10_t P = CK.PA;
    v2f* bre = (v2f*)buf;
    v2f* bim = (v2f*)(buf + DIM);
    #pragma unroll
    for (int j = 0; j < 8; j++) {
        uint32_t s = (wb ^ P.WL[j]) >> 1;
        bre[s] = PRE[j]; bim[s] = PIM[j];
    }
    __asm__ volatile("s_waitcnt lgkmcnt(0)" ::: "memory");
    #pragma unroll
    for (int j = 0; j < 8; j++) {
        uint32_t s0 = rb ^ P.RL[j], s1 = rb ^ P.RL[j | 8];
        v2f re, im;
        re.x = buf[s0];       re.y = buf[s1];
        im.x = buf[DIM + s0]; im.y = buf[DIM + s1];
        PRE[j] = re; PIM[j] = im;
    }
}

// cross-wave P_b: pre-barrier (drain P_a reads block-wide), write, barrier, read
__device__ __forceinline__ void pb_pass(v2f (&PRE)[8], v2f (&PIM)[8],
                                        float* buf, uint32_t wb, uint32_t rb) {
    constexpr Pass_t P = CK.PB;
    v2f* bre = (v2f*)buf;
    v2f* bim = (v2f*)(buf + DIM);
    __syncthreads();
    #pragma unroll
    for (int j = 0; j < 8; j++) {
        uint32_t s = (wb ^ P.WL[j]) >> 1;
        bre[s] = PRE[j]; bim[s] = PIM[j];
    }
    __syncthreads();
    #pragma unroll
    for (int j = 0; j < 8; j++) {
        uint32_t s0 = rb ^ P.RL[j], s1 = rb ^ P.RL[j | 8];
        v2f re, im;
        re.x = buf[s0];       re.y = buf[s1];
        im.x = buf[DIM + s0]; im.y = buf[DIM + s1];
        PRE[j] = re; PIM[j] = im;
    }
}

// cross-wave rebase P_c, runtime layer index (R12 verbatim)
__device__ __forceinline__ void rebase_pass(v2f (&PRE)[8], v2f (&PIM)[8],
                                            float* buf, int tid, int l) {
    const Pass_t& P = CK.P1[l];
    uint32_t wb = 0, rb = 0;
    #pragma unroll
    for (int j = 0; j < 8; j++) {
        uint32_t sel = (uint32_t)(-(int)((tid >> j) & 1));
        wb ^= sel & P.WT[j];
        rb ^= sel & P.RT[j];
    }
    v2f* bre = (v2f*)buf;
    v2f* bim = (v2f*)(buf + DIM);
    #pragma unroll
    for (int j = 0; j < 8; j++) {
        uint32_t s = (wb ^ P.WL[j]) >> 1;
        bre[s] = PRE[j]; bim[s] = PIM[j];
    }
    __syncthreads();
    #pragma unroll
    for (int j = 0; j < 8; j++) {
        uint32_t s0 = rb ^ P.RL[j], s1 = rb ^ P.RL[j | 8];
        v2f re, im;
        re.x = buf[s0];       re.y = buf[s1];
        im.x = buf[DIM + s0]; im.y = buf[DIM + s1];
        PRE[j] = re; PIM[j] = im;
    }
}

__global__ __launch_bounds__(TPB) void qsim_kernel(
    const float* __restrict__ x,        // [512,12]
    const float* __restrict__ weights,  // [6,12,3]
    const float* __restrict__ Wp,       // [12]
    const float* __restrict__ bptr,     // [1]
    float* __restrict__ out)            // [512]
{
    __shared__ float  lds[2 * 2 * DIM]; // bufA [0,8192): P_a/P_b; bufB: rebase
    __shared__ float4 smat[NLAYERS * NQ];
    __shared__ float  scs[NQ], sss[NQ];
    __shared__ float  red[4];

    const int tid = threadIdx.x;
    const int b   = blockIdx.x;

    if (tid < NQ) {
        float s_, c_;
        sincosf(0.5f * x[b * NQ + tid], &s_, &c_);
        scs[tid] = c_; sss[tid] = s_;
    }
    if (tid < NLAYERS * NQ) {
        float phi   = weights[tid * 3 + 0];
        float theta = weights[tid * 3 + 1];
        float omega = weights[tid * 3 + 2];
        float st, ct; sincosf(0.5f * theta, &st, &ct);
        float sp, cp; sincosf(0.5f * (phi + omega), &sp, &cp);
        float sm, cm; sincosf(0.5f * (phi - omega), &sm, &cm);
        smat[tid] = make_float4(cp * ct, -sp * ct, -cm * st, -sm * st);
    }
    __syncthreads();

    // init, identity basis: k = (tid<<4)|(h<<3)|j; local bits 0-2 <-> wires
    // 11,10,9; pack bit 3 <-> wire 8; tid bit j <-> wire 7-j.
    float base = 1.0f;
    #pragma unroll
    for (int j = 0; j < 8; j++) {
        int w = 7 - j;
        base *= ((tid >> j) & 1) ? sss[w] : scs[w];
    }
    v2f PRE[8], PIM[8];
    float c8 = scs[8], s8 = sss[8];
    #pragma unroll
    for (int j = 0; j < 8; j++) {
        float a = base;
        #pragma unroll
        for (int p = 0; p < 3; p++) {
            int w = NQ - 1 - p;
            a *= ((j >> p) & 1) ? sss[w] : scs[w];
        }
        PRE[j].x = a * c8;  PRE[j].y = a * s8;
        PIM[j].x = 0.0f;    PIM[j].y = 0.0f;
    }

    // fixed-pass address bases
    uint32_t pawb = 0, parb = 0, pbwb = 0, pbrb = 0;
    #pragma unroll
    for (int j = 0; j < 6; j++) {
        uint32_t sel = (uint32_t)(-(int)((tid >> j) & 1));
        pawb ^= sel & CK.PA.WT[j]; parb ^= sel & CK.PA.RT[j];
    }
    #pragma unroll
    for (int j = 0; j < 8; j++) {
        uint32_t sel = (uint32_t)(-(int)((tid >> j) & 1));
        pbwb ^= sel & CK.PB.WT[j]; pbrb ^= sel & CK.PB.RT[j];
    }
    {
        uint32_t wvb = (uint32_t)(tid & 0xC0) << 4;   // wave id -> slot bits 10,11
        pawb |= wvb; parb |= wvb;
    }

    float* bufA = lds;
    float* bufB = lds + 2 * DIM;

    #pragma clang loop unroll(disable)
    for (int l = 0; l < NLAYERS; l++) {
        if (l > 0) rebase_pass(PRE, PIM, bufB, tid, l);
        const int sb = l * NQ;
        gate_q<0>(PRE, PIM, smat[sb + 11]);
        gate_q<1>(PRE, PIM, smat[sb + 10]);
        gate_q<2>(PRE, PIM, smat[sb + 9]);
        pack_gate(PRE, PIM, smat[sb + 8]);
        pa_pass(PRE, PIM, bufA, pawb, parb);
        gate_q<0>(PRE, PIM, smat[sb + 7]);
        gate_q<1>(PRE, PIM, smat[sb + 6]);
        gate_q<2>(PRE, PIM, smat[sb + 5]);
        pack_gate(PRE, PIM, smat[sb + 4]);
        pb_pass(PRE, PIM, bufA, pbwb, pbrb);
        gate_q<0>(PRE, PIM, smat[sb + 3]);
        gate_q<1>(PRE, PIM, smat[sb + 2]);
        gate_q<2>(PRE, PIM, smat[sb + 1]);
        pack_gate(PRE, PIM, smat[sb + 0]);
    }

    // expectation: coef = b + sum_p W[11-p]*(1-2*bit_p(i(k))), packed halves
    const float bv = bptr[0];
    float wbT[NQ];
    #pragma unroll
    for (int p = 0; p < NQ; p++) {
        uint32_t row = CK.frow[p];
        int tp = __popc(tid & (int)(row >> 4)) & 1;
        float Wv = Wp[NQ - 1 - p];
        wbT[p] = tp ? -Wv : Wv;
    }
    v2f acc2 = {0.0f, 0.0f};
    #pragma unroll
    for (int j = 0; j < 8; j++) {
        float cx = bv, cy = bv;
        #pragma unroll
        for (int p = 0; p < NQ; p++) {
            uint32_t row = CK.frow[p];
            float s = (__popc(j & (int)(row & 7u)) & 1) ? -wbT[p] : wbT[p];
            cx += s;
            cy += (row & 8u) ? -s : s;
        }
        v2f c = {cx, cy};
        acc2 += (PRE[j] * PRE[j] + PIM[j] * PIM[j]) * c;
    }
    float acc = acc2.x + acc2.y;
    #pragma unroll
    for (int off = 32; off > 0; off >>= 1)
        acc += __shfl_down(acc, off, 64);
    if ((tid & 63) == 0) red[tid >> 6] = acc;
    __syncthreads();
    if (tid == 0) out[b] = red[0] + red[1] + red[2] + red[3];
}

extern "C" void kernel_launch(void* const* d_in, const int* in_sizes, int n_in,
                              void* d_out, int out_size, void* d_ws, size_t ws_size,
                              hipStream_t stream) {
    const float* x       = (const float*)d_in[0];
    const float* weights = (const float*)d_in[1];
    const float* W       = (const float*)d_in[2];
    const float* bptr    = (const float*)d_in[3];
    qsim_kernel<<<512, TPB, 0, stream>>>(x, weights, W, bptr, (float*)d_out);
}